// Round 1
// baseline (196.148 us; speedup 1.0000x reference)
//
#include <hip/hip_runtime.h>
#include <math.h>

#define TM   16      // samples per workgroup
#define NTH  256     // threads per workgroup (4 waves)

__device__ __forceinline__ float waveSum(float v) {
#pragma unroll
  for (int off = 32; off; off >>= 1) v += __shfl_xor(v, off, 64);
  return v;
}

__device__ __forceinline__ float siluf(float x) { return x / (1.0f + expf(-x)); }

// Per-sample PL helper: given 5 selected exp-logits (uniform across wave), Z,
// each lane accumulates its share of the 120-permutation sum of
// prod_j 1/(Z - prefix). Lane p handles perms p and p+64.
__device__ __forceinline__ float permSum(const float se0, const float se1,
                                         const float se2, const float se3,
                                         const float se4, float Z, int lane) {
  float psum = 0.0f;
#pragma unroll
  for (int pp = 0; pp < 2; ++pp) {
    int p = lane + pp * 64;
    if (p < 120) {
      int rem = p;
      unsigned avail = 0x43210u;  // nibble i holds value i
      float c = 0.0f;
      float prod = Z;             // denominator for step 0
#pragma unroll
      for (int j = 0; j < 4; ++j) {
        const int fct = (j == 0) ? 24 : (j == 1) ? 6 : (j == 2) ? 2 : 1;
        int q = rem / fct; rem -= q * fct;
        int sh = q * 4;
        int dg = (avail >> sh) & 0xF;
        avail = (avail & ((1u << sh) - 1u)) | ((avail >> (sh + 4)) << sh);
        float ev = (dg == 0) ? se0 : (dg == 1) ? se1 : (dg == 2) ? se2
                 : (dg == 3) ? se3 : se4;
        c += ev;
        prod *= (Z - c);
      }
      psum += 1.0f / prod;
    }
  }
  return psum;
}

__global__ __launch_bounds__(NTH, 2)
void pcf_fused(const float* __restrict__ ua, const float* __restrict__ ub,
               const float* __restrict__ alog, const float* __restrict__ W1,
               const float* __restrict__ b1, const float* __restrict__ W2,
               const float* __restrict__ b2, const float* __restrict__ V1,
               const float* __restrict__ c1, const float* __restrict__ V2,
               const float* __restrict__ c2, const float* __restrict__ V3,
               const float* __restrict__ c3, float* __restrict__ out)
{
  __shared__ float sStage[4096];    // 16 KB weight staging chunk
  __shared__ float sZ1[TM * 256];   // 16 KB
  __shared__ float sZ2[TM * 256];   // 16 KB
  __shared__ float sH [TM * 128];   // 8 KB  (reused for beta logits)
  __shared__ float sCtx[TM * 64];   // 4 KB
  __shared__ int   sSelA[TM * 5];
  __shared__ float sLpA[TM];

  const int t    = threadIdx.x;
  const int lane = t & 63;
  const int wave = t >> 6;
  const int s0   = blockIdx.x * TM;

  //============ Phase A: alpha Gumbel-top5 + exact PL log-prob ============
  {
    float la = alog[lane];
    float ea = expf(la);
    float Za = waveSum(ea);
    for (int si = 0; si < 4; ++si) {
      int s = wave * 4 + si;
      int b = s0 + s;
      float u = ua[(size_t)b * 64 + lane];
      float g = -logf(-logf(fmaxf(u, 1e-10f)));
      float vcur = la + g;
      float sel_e[5]; int sel_i[5];
#pragma unroll
      for (int r = 0; r < 5; ++r) {
        float bv = vcur; int bi = lane;
#pragma unroll
        for (int off = 32; off; off >>= 1) {
          float ov = __shfl_xor(bv, off, 64);
          int   oi = __shfl_xor(bi, off, 64);
          if (ov > bv || (ov == bv && oi < bi)) { bv = ov; bi = oi; }
        }
        sel_i[r] = bi;
        sel_e[r] = __shfl(ea, bi, 64);
        if (lane == bi) vcur = -INFINITY;
      }
      float isSel = (vcur == -INFINITY) ? 1.0f : 0.0f;
      out[(size_t)b * 128 + lane] = isSel;                 // alpha config
      float sl = waveSum(isSel != 0.0f ? la : 0.0f);       // sum selected logits
      float S  = waveSum(permSum(sel_e[0], sel_e[1], sel_e[2], sel_e[3],
                                 sel_e[4], Za, lane));
      if (lane == 0) {
        sLpA[s] = sl + logf(S);
#pragma unroll
        for (int r = 0; r < 5; ++r) sSelA[s * 5 + r] = sel_i[r];
      }
    }
  }
  __syncthreads();

  //============ Phase H: h = silu(sum of 5 W1 rows + b1) ============
  {
    int j   = t & 127;
    int sgh = t >> 7;      // 0..1
#pragma unroll
    for (int ss = 0; ss < 8; ++ss) {
      int s = sgh * 8 + ss;
      int i0 = sSelA[s * 5 + 0], i1 = sSelA[s * 5 + 1], i2 = sSelA[s * 5 + 2];
      int i3 = sSelA[s * 5 + 3], i4 = sSelA[s * 5 + 4];
      float acc = b1[j] + W1[i0 * 128 + j] + W1[i1 * 128 + j]
                + W1[i2 * 128 + j] + W1[i3 * 128 + j] + W1[i4 * 128 + j];
      sH[s * 128 + j] = siluf(acc);
    }
  }
  __syncthreads();

  //============ GEMM1: ctx[16][64] = h @ W2 + b2 (no act) ============
  {
    int colg = t & 31, sg = t >> 5;
    int cc = colg * 2, ss = sg * 2;
    float a00 = 0, a01 = 0, a10 = 0, a11 = 0;
    for (int k0 = 0; k0 < 128; k0 += 64) {
      __syncthreads();
      for (int i = t; i < 1024; i += NTH)
        ((float4*)sStage)[i] = ((const float4*)(W2 + k0 * 64))[i];
      __syncthreads();
#pragma unroll 16
      for (int kk = 0; kk < 64; ++kk) {
        float h0 = sH[ss * 128 + k0 + kk];
        float h1 = sH[(ss + 1) * 128 + k0 + kk];
        float w0 = sStage[kk * 64 + cc];
        float w1 = sStage[kk * 64 + cc + 1];
        a00 += h0 * w0; a01 += h0 * w1;
        a10 += h1 * w0; a11 += h1 * w1;
      }
    }
    sCtx[ss * 64 + cc]           = a00 + b2[cc];
    sCtx[ss * 64 + cc + 1]       = a01 + b2[cc + 1];
    sCtx[(ss + 1) * 64 + cc]     = a10 + b2[cc];
    sCtx[(ss + 1) * 64 + cc + 1] = a11 + b2[cc + 1];
  }
  __syncthreads();

  //============ GEMM2: z1[16][256] = silu(ctx @ V1[64:,:] + c1) ============
  {
    int colg = t & 63, sg = t >> 6;
    int cc = colg * 4, ss = sg * 4;
    float acc[4][4] = {};
    for (int k0 = 0; k0 < 64; k0 += 16) {
      __syncthreads();
      for (int i = t; i < 1024; i += NTH)
        ((float4*)sStage)[i] = ((const float4*)(V1 + (size_t)(64 + k0) * 256))[i];
      __syncthreads();
#pragma unroll
      for (int kk = 0; kk < 16; ++kk) {
        float4 w = *(const float4*)&sStage[kk * 256 + cc];
        float x0 = sCtx[(ss + 0) * 64 + k0 + kk];
        float x1 = sCtx[(ss + 1) * 64 + k0 + kk];
        float x2 = sCtx[(ss + 2) * 64 + k0 + kk];
        float x3 = sCtx[(ss + 3) * 64 + k0 + kk];
        acc[0][0] += x0 * w.x; acc[0][1] += x0 * w.y; acc[0][2] += x0 * w.z; acc[0][3] += x0 * w.w;
        acc[1][0] += x1 * w.x; acc[1][1] += x1 * w.y; acc[1][2] += x1 * w.z; acc[1][3] += x1 * w.w;
        acc[2][0] += x2 * w.x; acc[2][1] += x2 * w.y; acc[2][2] += x2 * w.z; acc[2][3] += x2 * w.w;
        acc[3][0] += x3 * w.x; acc[3][1] += x3 * w.y; acc[3][2] += x3 * w.z; acc[3][3] += x3 * w.w;
      }
    }
    float4 cb = *(const float4*)&c1[cc];
#pragma unroll
    for (int i = 0; i < 4; ++i) {
      float4 o;
      o.x = siluf(acc[i][0] + cb.x); o.y = siluf(acc[i][1] + cb.y);
      o.z = siluf(acc[i][2] + cb.z); o.w = siluf(acc[i][3] + cb.w);
      *(float4*)&sZ1[(ss + i) * 256 + cc] = o;
    }
  }
  __syncthreads();

  //============ GEMM3: z2[16][256] = silu(z1 @ V2 + c2) ============
  {
    int colg = t & 63, sg = t >> 6;
    int cc = colg * 4, ss = sg * 4;
    float acc[4][4] = {};
    for (int k0 = 0; k0 < 256; k0 += 16) {
      __syncthreads();
      for (int i = t; i < 1024; i += NTH)
        ((float4*)sStage)[i] = ((const float4*)(V2 + (size_t)k0 * 256))[i];
      __syncthreads();
#pragma unroll
      for (int kk = 0; kk < 16; ++kk) {
        float4 w = *(const float4*)&sStage[kk * 256 + cc];
        float x0 = sZ1[(ss + 0) * 256 + k0 + kk];
        float x1 = sZ1[(ss + 1) * 256 + k0 + kk];
        float x2 = sZ1[(ss + 2) * 256 + k0 + kk];
        float x3 = sZ1[(ss + 3) * 256 + k0 + kk];
        acc[0][0] += x0 * w.x; acc[0][1] += x0 * w.y; acc[0][2] += x0 * w.z; acc[0][3] += x0 * w.w;
        acc[1][0] += x1 * w.x; acc[1][1] += x1 * w.y; acc[1][2] += x1 * w.z; acc[1][3] += x1 * w.w;
        acc[2][0] += x2 * w.x; acc[2][1] += x2 * w.y; acc[2][2] += x2 * w.z; acc[2][3] += x2 * w.w;
        acc[3][0] += x3 * w.x; acc[3][1] += x3 * w.y; acc[3][2] += x3 * w.z; acc[3][3] += x3 * w.w;
      }
    }
    float4 cb = *(const float4*)&c2[cc];
#pragma unroll
    for (int i = 0; i < 4; ++i) {
      float4 o;
      o.x = siluf(acc[i][0] + cb.x); o.y = siluf(acc[i][1] + cb.y);
      o.z = siluf(acc[i][2] + cb.z); o.w = siluf(acc[i][3] + cb.w);
      *(float4*)&sZ2[(ss + i) * 256 + cc] = o;
    }
  }
  __syncthreads();

  //============ GEMM4: beta_logits[16][64] = z2 @ V3 + c3 ============
  {
    int colg = t & 31, sg = t >> 5;
    int cc = colg * 2, ss = sg * 2;
    float a00 = 0, a01 = 0, a10 = 0, a11 = 0;
    for (int k0 = 0; k0 < 256; k0 += 64) {
      __syncthreads();
      for (int i = t; i < 1024; i += NTH)
        ((float4*)sStage)[i] = ((const float4*)(V3 + (size_t)k0 * 64))[i];
      __syncthreads();
#pragma unroll 16
      for (int kk = 0; kk < 64; ++kk) {
        float z0 = sZ2[ss * 256 + k0 + kk];
        float z1v = sZ2[(ss + 1) * 256 + k0 + kk];
        float w0 = sStage[kk * 64 + cc];
        float w1 = sStage[kk * 64 + cc + 1];
        a00 += z0 * w0; a01 += z0 * w1;
        a10 += z1v * w0; a11 += z1v * w1;
      }
    }
    float* sBL = sH;  // sH dead after GEMM1
    sBL[ss * 64 + cc]           = a00 + c3[cc];
    sBL[ss * 64 + cc + 1]       = a01 + c3[cc + 1];
    sBL[(ss + 1) * 64 + cc]     = a10 + c3[cc];
    sBL[(ss + 1) * 64 + cc + 1] = a11 + c3[cc + 1];
  }
  __syncthreads();

  //============ Phase B: beta Gumbel-top5 + PL + final log_probs ============
  {
    const float* sBL = sH;
    for (int si = 0; si < 4; ++si) {
      int s = wave * 4 + si;
      int b = s0 + s;
      float bl = sBL[s * 64 + lane];
      float eb = expf(bl);
      float Zb = waveSum(eb);
      float u = ub[(size_t)b * 64 + lane];
      float g = -logf(-logf(fmaxf(u, 1e-10f)));
      float vcur = bl + g;
      float sel_e[5];
#pragma unroll
      for (int r = 0; r < 5; ++r) {
        float bv = vcur; int bi = lane;
#pragma unroll
        for (int off = 32; off; off >>= 1) {
          float ov = __shfl_xor(bv, off, 64);
          int   oi = __shfl_xor(bi, off, 64);
          if (ov > bv || (ov == bv && oi < bi)) { bv = ov; bi = oi; }
        }
        sel_e[r] = __shfl(eb, bi, 64);
        if (lane == bi) vcur = -INFINITY;
      }
      float isSel = (vcur == -INFINITY) ? 1.0f : 0.0f;
      out[(size_t)b * 128 + 64 + lane] = isSel;            // beta config
      float sl = waveSum(isSel != 0.0f ? bl : 0.0f);
      float S  = waveSum(permSum(sel_e[0], sel_e[1], sel_e[2], sel_e[3],
                                 sel_e[4], Zb, lane));
      if (lane == 0)
        out[(size_t)8192 * 128 + b] = sLpA[s] + sl + logf(S);
    }
  }
}

extern "C" void kernel_launch(void* const* d_in, const int* in_sizes, int n_in,
                              void* d_out, int out_size, void* d_ws, size_t ws_size,
                              hipStream_t stream) {
  const float* ua   = (const float*)d_in[0];
  const float* ub   = (const float*)d_in[1];
  const float* alog = (const float*)d_in[2];
  const float* W1   = (const float*)d_in[3];
  const float* b1   = (const float*)d_in[4];
  const float* W2   = (const float*)d_in[5];
  const float* b2   = (const float*)d_in[6];
  const float* V1   = (const float*)d_in[7];
  const float* c1   = (const float*)d_in[8];
  const float* V2   = (const float*)d_in[9];
  const float* c2   = (const float*)d_in[10];
  const float* V3   = (const float*)d_in[11];
  const float* c3   = (const float*)d_in[12];
  float* out = (float*)d_out;

  pcf_fused<<<dim3(8192 / TM), dim3(NTH), 0, stream>>>(
      ua, ub, alog, W1, b1, W2, b2, V1, c1, V2, c2, V3, c3, out);
}